// Round 15
// baseline (116.885 us; speedup 1.0000x reference)
//
#include <hip/hip_runtime.h>
#include <stdint.h>
#include <math.h>

typedef unsigned short u16;
typedef unsigned int   u32;
typedef __bf16 bf16x8 __attribute__((ext_vector_type(8)));
typedef float  f32x4  __attribute__((ext_vector_type(4)));

#define L_IN 784
#define KT2 25            // 25 K-tiles of 32 (800 >= 784; pad zeros in B)

__device__ __forceinline__ u32 f2bf(float f){
    u32 u = __float_as_uint(f);
    return (u + 0x7fffu + ((u >> 16) & 1u)) >> 16;   // RNE truncate to bf16
}

__device__ __forceinline__ void gload16(const void* g, void* l){
    __builtin_amdgcn_global_load_lds(
        (const __attribute__((address_space(1))) unsigned char*)g,
        (__attribute__((address_space(3))) unsigned char*)l, 16, 0, 0);
}

// ---------------------------------------------------------------------------
// K0: merged prep, coalesced reads (validated r11-r14).
// Part 1: W0 -> Bimg fragment-broadcast bf16 at BK=32:
//   Bimg[(kt*8 + nt)*512 + lane*8 + j] = W0[k][col],
//   col = nt*16 + (lane&15), k = kt*32 + (lane>>4)*8 + j. Zero for k>=784.
// Part 2: Wa/Wb -> Wab fragment image (validated r7-r14).
// ---------------------------------------------------------------------------
__global__ void prep_all(const float* __restrict__ W0, const float* __restrict__ Wa,
                         const float* __restrict__ Wb, u16* __restrict__ Bimg,
                         u16* __restrict__ Wab){
    int idx = blockIdx.x * 256 + threadIdx.x;
    if (idx < KT2 * 32 * 128){
        int col = idx & 127, k = idx >> 7;
        float v = (k < L_IN) ? W0[idx] : 0.f;        // coalesced: idx = k*128+col
        int kt = k >> 5, lk = (k >> 3) & 3, j = k & 7;
        Bimg[((kt * 8 + (col >> 4)) << 9) + (lk * 16 + (col & 15)) * 8 + j]
            = (u16)f2bf(v);
    } else if (idx < KT2 * 32 * 128 + 16384){
        int i2 = idx - KT2 * 32 * 128;
        int jj = i2 & 7, l = (i2 >> 3) & 63, ks = (i2 >> 9) & 1;
        int nt = (i2 >> 10) & 1, h = (i2 >> 11) & 1, mat = (i2 >> 12) & 1;
        int s = ks * 32 + (l >> 4) * 8 + jj, d = nt * 16 + (l & 15);
        const float* W = mat ? Wb : Wa;
        Wab[i2] = (u16)f2bf(W[h * 2048 + s * 32 + d]);
    }
}

// ---------------------------------------------------------------------------
// K1: FUSED relu(h@W0+b0) -> gated attention -> exp -> pooling partials.
// PIPE-SPLIT version: A stays on the LDS pipe (global_load_lds, 3 x 8KB,
// 2-deep, raw s_barrier — r12/r13 validated); B moves to the L1/TA pipe
// (register loads of 1KB lock-step broadcast blocks from L2-resident Bimg —
// r9 validated path). LDS traffic drops 56 -> 16 KB/block/tile; B's 32KB
// rides the separate vector-return path and overlaps.
// FIFO (in-order vmcnt): per tile, B(kt) loads are issued BEFORE
// stageA(kt+2), so the compiler's pre-MFMA B-wait retires A(kt+1) (older)
// as a side effect while A(kt+2) stays in flight ~2 tile periods. The
// explicit end-of-tile vmcnt(2) (edge vmcnt(0)) pins the r13 induction.
// ---------------------------------------------------------------------------
__global__ __launch_bounds__(256, 4)
void fc_fused(const float* __restrict__ hG, const u16* __restrict__ Bimg,
              const u16* __restrict__ Wab, const float* __restrict__ b0,
              const float* __restrict__ ba, const float* __restrict__ bb,
              const float* __restrict__ Wc, const float* __restrict__ bc,
              float* __restrict__ partials, int N){
    __shared__ __align__(16) char Asm[3 * 8192];     // A only: 3 x 8KB

    const int t    = threadIdx.x;
    const int lane = t & 63;
    const int w    = t >> 6;
    const int lr   = lane & 15;          // A-row / B-col within 16
    const int lk   = lane >> 4;          // k-slot 0..3 (8 k each)
    const int gb   = blockIdx.x;
    const long rowBase = (long)gb * 64;

    // ---- A staging geometry (validated r12/r13): instr j (0,1): granule
    // g = j*256+t; row = j*32+(t>>3); slot c = t&7; src granule cs = c^(row&7)
    // -> per-thread constant. 8 fully-used 128B lines per wave-instr.
    const int cs = (t & 7) ^ ((t >> 3) & 7);
    const float* srcp[2];
    #pragma unroll
    for (int j = 0; j < 2; ++j){
        long grow = rowBase + j * 32 + (t >> 3);
        if (grow >= N) grow = N - 1;                 // clamp; e=0 masks later
        srcp[j] = hG + grow * L_IN + cs * 4;
    }

    f32x4 acc[8];
    #pragma unroll
    for (int nt = 0; nt < 8; ++nt) acc[nt] = (f32x4)0.f;

    auto stageA = [&](int kt, char* buf){
        // pad: kt==24, cs>=4 -> k>=784 invalid; read k=cs*4 (B zero-pads).
        const int off = (kt == KT2 - 1 && cs >= 4) ? 0 : kt * 32;
        #pragma unroll
        for (int j = 0; j < 2; ++j)
            gload16(srcp[j] + off, buf + (j * 256 + t) * 16);
    };

    char* pa0 = &Asm[0];
    char* pa1 = &Asm[8192];
    char* pa2 = &Asm[16384];

    stageA(0, pa0);
    stageA(1, pa1);
    __syncthreads();                                 // one-time full drain

    const int rA = w * 16 + lr;

    #pragma unroll 1
    for (int kt = 0; kt < KT2; ++kt){
        // ---- B fragments: register loads, 1KB lock-step broadcast (oldest
        //      in this tile's FIFO; their wait retires A(kt+1) for free) ----
        const u16* bp = Bimg + (size_t)kt * 4096 + lane * 8;
        bf16x8 bfr[8];
        #pragma unroll
        for (int nt = 0; nt < 8; ++nt)
            bfr[nt] = *(const bf16x8*)(bp + nt * 512);
        __builtin_amdgcn_sched_barrier(0);

        // ---- stage A(kt+2) (youngest: survives every B wait) ----
        if (kt + 2 < KT2) stageA(kt + 2, pa2);
        __builtin_amdgcn_sched_barrier(0);

        // ---- A fragment from LDS (swizzled) + cvt ----
        const char* base = pa0 + rA * 128;
        f32x4 lo = *(const f32x4*)(base + (((lk * 2)    ) ^ (rA & 7)) * 16);
        f32x4 hi = *(const f32x4*)(base + (((lk * 2) + 1) ^ (rA & 7)) * 16);
        bf16x8 af;
        #pragma unroll
        for (int j = 0; j < 4; ++j){
            af[j]     = (__bf16)lo[j];
            af[4 + j] = (__bf16)hi[j];
        }
        // ---- MFMA ----
        #pragma unroll
        for (int nt = 0; nt < 8; ++nt)
            acc[nt] = __builtin_amdgcn_mfma_f32_16x16x32_bf16(af, bfr[nt], acc[nt], 0, 0, 0);

        // ---- end-of-tile: ensure {B(kt), A(kt+1)} retired, keep A(kt+2)
        //      in flight; then raw barrier (no full drain) ----
        if (kt + 1 < KT2){
            if (kt + 2 < KT2) asm volatile("s_waitcnt vmcnt(2)" ::: "memory");
            else              asm volatile("s_waitcnt vmcnt(0)" ::: "memory");
            __builtin_amdgcn_sched_barrier(0);
            __builtin_amdgcn_s_barrier();
            __builtin_amdgcn_sched_barrier(0);
        }
        // rotate A buffers (3-cycle)
        char* ta = pa0; pa0 = pa1; pa1 = pa2; pa2 = ta;
    }

    __syncthreads();   // full drain; LDS reusable

    // ---- bias + relu; x-tile bf16 into Asm[0..16K) (swizzled) ----
    u16*   xs   = (u16*)&Asm[0];          // 64 x 128 bf16 = 16 KB
    float* pbuf = (float*)&Asm[16384];    // 4 x 132 f32 cross-wave buffer
    #pragma unroll
    for (int nt = 0; nt < 8; ++nt){
        float bias = b0[nt * 16 + lr];
        #pragma unroll
        for (int j = 0; j < 4; ++j){
            float v = acc[nt][j] + bias;
            v = v > 0.f ? v : 0.f;
            acc[nt][j] = v;
            int row = w * 16 + lk * 4 + j;
            int col = nt * 16 + lr;
            xs[row * 128 + ((((col >> 3) ^ (row & 15))) << 3) + (col & 7)] = (u16)f2bf(v);
        }
    }
    __syncthreads();

    // ---- per-head projections via MFMA + logits + exp (validated r7) ----
    float eh[2][4];
    #pragma unroll
    for (int h = 0; h < 2; ++h){
        bf16x8 xa[2];
        #pragma unroll
        for (int ks = 0; ks < 2; ++ks){
            int row = w * 16 + lr;
            int ch  = (h * 8 + ks * 4 + lk) ^ (row & 15);
            xa[ks] = *(const bf16x8*)&xs[row * 128 + ch * 8];
        }
        f32x4 Ca[2], Cg[2];
        #pragma unroll
        for (int nt = 0; nt < 2; ++nt){ Ca[nt] = (f32x4)0.f; Cg[nt] = (f32x4)0.f; }
        #pragma unroll
        for (int nt = 0; nt < 2; ++nt)
            #pragma unroll
            for (int ks = 0; ks < 2; ++ks){
                bf16x8 wfa = *(const bf16x8*)(Wab + ((size_t)(h*4 + nt*2 + ks) << 9) + lane * 8);
                bf16x8 wfb = *(const bf16x8*)(Wab + ((size_t)(8 + h*4 + nt*2 + ks) << 9) + lane * 8);
                Ca[nt] = __builtin_amdgcn_mfma_f32_16x16x32_bf16(xa[ks], wfa, Ca[nt], 0, 0, 0);
                Cg[nt] = __builtin_amdgcn_mfma_f32_16x16x32_bf16(xa[ks], wfb, Cg[nt], 0, 0, 0);
            }
        float pj[4];
        #pragma unroll
        for (int j = 0; j < 4; ++j){
            float s = 0.f;
            #pragma unroll
            for (int nt = 0; nt < 2; ++nt){
                int d = h * 32 + nt * 16 + lr;
                float av = tanhf(Ca[nt][j] + ba[d]);
                float gv = 1.f / (1.f + expf(-(Cg[nt][j] + bb[d])));
                s += av * gv * Wc[d];
            }
            pj[j] = s;
        }
        #pragma unroll
        for (int m = 1; m <= 8; m <<= 1)
            #pragma unroll
            for (int j = 0; j < 4; ++j)
                pj[j] += __shfl_xor(pj[j], m, 64);
        #pragma unroll
        for (int j = 0; j < 4; ++j){
            long row = rowBase + w * 16 + lk * 4 + j;
            // |A| <= sum|Wc|+|bc| (~7): exp safe in f32 without max-subtract
            eh[h][j] = (row < (long)N) ? expf(pj[j] + bc[h]) : 0.f;
        }
    }

    // ---- pooling: p[col] = sum over wave's 16 rows of e*x (f32 acc) ----
    float p[8];
    #pragma unroll
    for (int nt = 0; nt < 8; ++nt){
        const int h = nt >> 2;
        float s = 0.f;
        #pragma unroll
        for (int j = 0; j < 4; ++j) s += eh[h][j] * acc[nt][j];
        p[nt] = s;
    }
    #pragma unroll
    for (int m = 16; m <= 32; m <<= 1)
        #pragma unroll
        for (int nt = 0; nt < 8; ++nt)
            p[nt] += __shfl_xor(p[nt], m, 64);
    float es0 = eh[0][0] + eh[0][1] + eh[0][2] + eh[0][3];
    float es1 = eh[1][0] + eh[1][1] + eh[1][2] + eh[1][3];
    es0 += __shfl_xor(es0, 16, 64); es0 += __shfl_xor(es0, 32, 64);
    es1 += __shfl_xor(es1, 16, 64); es1 += __shfl_xor(es1, 32, 64);

    if (lk == 0){
        #pragma unroll
        for (int nt = 0; nt < 8; ++nt)
            pbuf[w * 132 + nt * 16 + lr] = p[nt];
    }
    if (lane == 0){
        pbuf[w * 132 + 128] = es0;
        pbuf[w * 132 + 129] = es1;
    }
    __syncthreads();
    if (t < 130){
        float s = pbuf[t] + pbuf[132 + t] + pbuf[264 + t] + pbuf[396 + t];
        partials[(size_t)gb * 132 + t] = s;
    }
}

// ---------------------------------------------------------------------------
// K2: first-stage reduction over blocks. 128 blocks; 2 independent accums.
// ---------------------------------------------------------------------------
__global__ __launch_bounds__(256)
void reduce1(const float* __restrict__ partials, float* __restrict__ red, int nb){
    const int b = blockIdx.x, t = threadIdx.x;
    if (t >= 130) return;
    float a0 = 0.f, a1 = 0.f;
    for (int r = b; r < nb; r += 256){
        a0 += partials[(size_t)r * 132 + t];
        if (r + 128 < nb) a1 += partials[(size_t)(r + 128) * 132 + t];
    }
    red[b * 132 + t] = a0 + a1;
}

// ---------------------------------------------------------------------------
// K3: combine 128 reduced rows (f64), M, logits, sigmoid, Y_hat. One block,
// parallel column sums + 64-lane shfl butterfly dot (fixed order).
// ---------------------------------------------------------------------------
__global__ __launch_bounds__(256)
void finalize2(const float* __restrict__ red, const float* __restrict__ Wcls,
               const float* __restrict__ bcls, float* __restrict__ out){
    __shared__ double colD[2][130];
    __shared__ float  M_s[128];
    const int t = threadIdx.x;
    const int c = t & 127, rh = t >> 7;
    {
        double s = 0.0;
        for (int r = rh * 64; r < rh * 64 + 64; r += 4){
            s += (double)red[(r + 0) * 132 + c] + (double)red[(r + 1) * 132 + c]
               + (double)red[(r + 2) * 132 + c] + (double)red[(r + 3) * 132 + c];
        }
        colD[rh][c] = s;
    }
    if (t < 4){
        int cc = 128 + (t & 1), hh = t >> 1;
        double s = 0.0;
        for (int r = hh * 64; r < hh * 64 + 64; r += 4){
            s += (double)red[(r + 0) * 132 + cc] + (double)red[(r + 1) * 132 + cc]
               + (double)red[(r + 2) * 132 + cc] + (double)red[(r + 3) * 132 + cc];
        }
        colD[hh][cc] = s;
    }
    __syncthreads();
    if (t < 128)
        M_s[t] = (float)((colD[0][t] + colD[1][t]) /
                         (colD[0][128 + (t >> 6)] + colD[1][128 + (t >> 6)]));
    __syncthreads();
    if (t < 64){
        double d = (double)M_s[t] * (double)Wcls[t]
                 + (double)M_s[t + 64] * (double)Wcls[t + 64];
        #pragma unroll
        for (int m = 1; m < 64; m <<= 1) d += __shfl_xor(d, m, 64);
        if (t == 0){
            double lg = d + (double)bcls[0];
            out[0] = (float)(1.0 / (1.0 + exp(-lg)));
            out[1] = (lg >= 0.0) ? 1.f : 0.f;
        }
    }
}

// ---------------------------------------------------------------------------
extern "C" void kernel_launch(void* const* d_in, const int* in_sizes, int n_in,
                              void* d_out, int out_size, void* d_ws, size_t ws_size,
                              hipStream_t stream){
    const float* hG   = (const float*)d_in[0];
    const float* W0   = (const float*)d_in[1];
    const float* b0   = (const float*)d_in[2];
    const float* Wa   = (const float*)d_in[3];
    const float* ba   = (const float*)d_in[4];
    const float* Wb   = (const float*)d_in[5];
    const float* bb   = (const float*)d_in[6];
    const float* Wc   = (const float*)d_in[7];
    const float* bc   = (const float*)d_in[8];
    const float* Wcls = (const float*)d_in[9];
    const float* bcls = (const float*)d_in[10];

    const int N    = in_sizes[0] / L_IN;
    const int nb64 = (N + 63) / 64;      // 64-row fused tiles

    char* ws = (char*)d_ws;
    u16* Bimg = (u16*)ws;                                  // 25*4096 u16 = 204800 B
    u16* Wab  = (u16*)(ws + 262144);                       // 16384 B
    size_t poff = 262144 + 16384;                          // 278528
    float* partials = (float*)(ws + poff);                 // nb64*132 f32
    size_t roff = poff + (((size_t)nb64 * 132 * 4 + 4095) & ~(size_t)4095);
    float* red  = (float*)(ws + roff);                     // 128*132 f32

    prep_all <<<(KT2 * 32 * 128 + 16384 + 255) / 256, 256, 0, stream>>>(W0, Wa, Wb, Bimg, Wab);
    fc_fused <<<nb64, 256, 0, stream>>>(hG, Bimg, Wab, b0, ba, bb, Wc, bc,
                                        partials, N);
    reduce1  <<<128, 256, 0, stream>>>(partials, red, nb64);
    finalize2<<<1, 256, 0, stream>>>(red, Wcls, bcls, (float*)d_out);
}

// Round 16
// 103.843 us; speedup vs baseline: 1.1256x; 1.1256x over previous
//
#include <hip/hip_runtime.h>
#include <stdint.h>
#include <math.h>

typedef unsigned short u16;
typedef unsigned int   u32;
typedef __bf16 bf16x8 __attribute__((ext_vector_type(8)));
typedef float  f32x4  __attribute__((ext_vector_type(4)));

#define L_IN 784
#define KT64 13           // 13 K-tiles of 64 (832 >= 784; pad zeros in B)
#define KT32 26           // B image is stored at 32-granularity: 26 slices

__device__ __forceinline__ u32 f2bf(float f){
    u32 u = __float_as_uint(f);
    return (u + 0x7fffu + ((u >> 16) & 1u)) >> 16;   // RNE truncate to bf16
}

__device__ __forceinline__ void gload16(const void* g, void* l){
    __builtin_amdgcn_global_load_lds(
        (const __attribute__((address_space(1))) unsigned char*)g,
        (__attribute__((address_space(3))) unsigned char*)l, 16, 0, 0);
}

// ---------------------------------------------------------------------------
// K0: merged prep, coalesced reads (validated r11-r15; extended to 26 slices).
// Part 1: W0 -> Bimg fragment-broadcast bf16 at 32-granularity:
//   Bimg[(kt32*8 + nt)*512 + lane*8 + j] = W0[k][col],
//   col = nt*16 + (lane&15), k = kt32*32 + (lane>>4)*8 + j. Zero for k>=784.
// Part 2: Wa/Wb -> Wab fragment image (validated r7-r15).
// ---------------------------------------------------------------------------
__global__ void prep_all(const float* __restrict__ W0, const float* __restrict__ Wa,
                         const float* __restrict__ Wb, u16* __restrict__ Bimg,
                         u16* __restrict__ Wab){
    int idx = blockIdx.x * 256 + threadIdx.x;
    if (idx < KT32 * 32 * 128){
        int col = idx & 127, k = idx >> 7;
        float v = (k < L_IN) ? W0[idx] : 0.f;        // coalesced: idx = k*128+col
        int kt = k >> 5, lk = (k >> 3) & 3, j = k & 7;
        Bimg[((kt * 8 + (col >> 4)) << 9) + (lk * 16 + (col & 15)) * 8 + j]
            = (u16)f2bf(v);
    } else if (idx < KT32 * 32 * 128 + 16384){
        int i2 = idx - KT32 * 32 * 128;
        int jj = i2 & 7, l = (i2 >> 3) & 63, ks = (i2 >> 9) & 1;
        int nt = (i2 >> 10) & 1, h = (i2 >> 11) & 1, mat = (i2 >> 12) & 1;
        int s = ks * 32 + (l >> 4) * 8 + jj, d = nt * 16 + (l & 15);
        const float* W = mat ? Wb : Wa;
        Wab[i2] = (u16)f2bf(W[h * 2048 + s * 32 + d]);
    }
}

// ---------------------------------------------------------------------------
// K1: FUSED relu(h@W0+b0) -> gated attention -> exp -> pooling partials.
// BK=64 variant of the r13 skeleton, targeting DRAM burst length:
//  - each A wave-instr now reads 4 rows x 256B CONTIGUOUS (vs 8 x 128B at
//    BK=32) -> 2x longer DRAM bursts on the column-sweep; 13 barrier rounds.
//  - A: 3 x 16KB slabs (2-deep HBM pipeline); B: 2 x 16KB slabs; 80KB LDS
//    -> 2 blocks/CU, in-flight DMA 64KB/CU (> r13's 32KB).
//  - decoupled FIFO (r12/r13 validated): per tile issue B(kt+1)[4] then
//    A(kt+2)[4]; ONLY vmcnt wait is end-of-tile vmcnt(4) retiring exactly
//    {A(kt+1),B(kt+1)}, leaving A(kt+2) in flight ~2 tile periods.
//  - granule-XOR swizzle: slot c of row r holds source granule c^(r&15);
//    read side XORs the same; 2-way bank aliasing (free, m136).
// ---------------------------------------------------------------------------
__global__ __launch_bounds__(256, 2)
void fc_fused(const float* __restrict__ hG, const u16* __restrict__ Bimg,
              const u16* __restrict__ Wab, const float* __restrict__ b0,
              const float* __restrict__ ba, const float* __restrict__ bb,
              const float* __restrict__ Wc, const float* __restrict__ bc,
              float* __restrict__ partials, int N){
    __shared__ __align__(16) char Asm[5 * 16384];    // A: 3 x 16KB, B: 2 x 16KB

    const int t    = threadIdx.x;
    const int lane = t & 63;
    const int w    = t >> 6;
    const int lr   = lane & 15;          // A-row / B-col within 16
    const int lk   = lane >> 4;          // k-slot 0..3 (8 k each, per 32-half)
    const int gb   = blockIdx.x;
    const long rowBase = (long)gb * 64;

    // ---- A staging geometry: instr j (0..3): granule g = j*256+t (16B);
    // row = g>>4 = j*16 + (t>>4); slot = t&15; source granule
    // cs = slot ^ (row&15) = (t&15)^((t>>4)&15) — per-thread constant.
    // Each wave-instr covers 4 rows x 256B contiguous.
    const int cs = (t & 15) ^ ((t >> 4) & 15);
    const float* srcp[4];
    #pragma unroll
    for (int j = 0; j < 4; ++j){
        long grow = rowBase + j * 16 + (t >> 4);
        if (grow >= N) grow = N - 1;                 // clamp; e=0 masks later
        srcp[j] = hG + grow * L_IN + cs * 4;
    }
    const char* BimgB = (const char*)Bimg;

    f32x4 acc[8];
    #pragma unroll
    for (int nt = 0; nt < 8; ++nt) acc[nt] = (f32x4)0.f;

    auto stageA = [&](int kt, char* buf){
        // pad: kt==12, cs>=4 -> k = 768+cs*4 >= 784 invalid; read k=cs*4
        // (in-bounds; B zero-pads those k so the value is don't-care).
        const int off = (kt == KT64 - 1 && cs >= 4) ? 0 : kt * 64;
        #pragma unroll
        for (int j = 0; j < 4; ++j)
            gload16(srcp[j] + off, buf + (j * 256 + t) * 16);
    };
    auto stageB = [&](int kt, char* buf){
        #pragma unroll
        for (int i = 0; i < 4; ++i)
            gload16(BimgB + (size_t)kt * 16384 + i * 4096 + t * 16,
                    buf + i * 4096 + t * 16);
    };

    char* pa0 = &Asm[0];     char* pa1 = &Asm[16384]; char* pa2 = &Asm[32768];
    char* pbR = &Asm[49152]; char* pbW = &Asm[65536];

    stageA(0, pa0);
    stageA(1, pa1);
    stageB(0, pbR);
    __syncthreads();                                 // one-time full drain

    const int rA = w * 16 + lr;

    #pragma unroll 1
    for (int kt = 0; kt < KT64; ++kt){
        // ---- stage B(kt+1) then A(kt+2) at the TOP (B older than A) ----
        __builtin_amdgcn_sched_barrier(0);
        if (kt + 1 < KT64) stageB(kt + 1, pbW);
        if (kt + 2 < KT64) stageA(kt + 2, pa2);
        __builtin_amdgcn_sched_barrier(0);

        // ---- B fragments from LDS image (lane-linear, conflict-free) ----
        bf16x8 bfr[16];
        #pragma unroll
        for (int q = 0; q < 16; ++q)
            bfr[q] = *(const bf16x8*)(pbR + q * 1024 + lane * 16);

        // ---- A fragments (kk = 0,1) from LDS (swizzled) + cvt + MFMA ----
        #pragma unroll
        for (int kk = 0; kk < 2; ++kk){
            const int g0 = kk * 8 + lk * 2;
            const char* base = pa0 + rA * 256;
            f32x4 lo = *(const f32x4*)(base + ((g0    ) ^ (rA & 15)) * 16);
            f32x4 hi = *(const f32x4*)(base + ((g0 + 1) ^ (rA & 15)) * 16);
            bf16x8 af;
            #pragma unroll
            for (int j = 0; j < 4; ++j){
                af[j]     = (__bf16)lo[j];
                af[4 + j] = (__bf16)hi[j];
            }
            #pragma unroll
            for (int nt = 0; nt < 8; ++nt)
                acc[nt] = __builtin_amdgcn_mfma_f32_16x16x32_bf16(
                              af, bfr[kk * 8 + nt], acc[nt], 0, 0, 0);
        }

        // ---- end-of-tile: retire {A(kt+1), B(kt+1)}, keep A(kt+2) flying ----
        if (kt + 1 < KT64){
            if (kt + 2 < KT64) asm volatile("s_waitcnt vmcnt(4)" ::: "memory");
            else               asm volatile("s_waitcnt vmcnt(0)" ::: "memory");
            __builtin_amdgcn_sched_barrier(0);
            __builtin_amdgcn_s_barrier();
            __builtin_amdgcn_sched_barrier(0);
        }
        // rotate: A 3-cycle, B 2-cycle
        char* ta = pa0; pa0 = pa1; pa1 = pa2; pa2 = ta;
        char* tb = pbR; pbR = pbW; pbW = tb;
    }

    __syncthreads();   // all DMAs retired; LDS reusable

    // ---- bias + relu; x-tile bf16 into Asm[0..16K) (swizzled) ----
    u16*   xs   = (u16*)&Asm[0];          // 64 x 128 bf16 = 16 KB
    float* pbuf = (float*)&Asm[16384];    // 4 x 132 f32 cross-wave buffer
    #pragma unroll
    for (int nt = 0; nt < 8; ++nt){
        float bias = b0[nt * 16 + lr];
        #pragma unroll
        for (int j = 0; j < 4; ++j){
            float v = acc[nt][j] + bias;
            v = v > 0.f ? v : 0.f;
            acc[nt][j] = v;
            int row = w * 16 + lk * 4 + j;
            int col = nt * 16 + lr;
            xs[row * 128 + ((((col >> 3) ^ (row & 15))) << 3) + (col & 7)] = (u16)f2bf(v);
        }
    }
    __syncthreads();

    // ---- per-head projections via MFMA + logits + exp (validated r7) ----
    float eh[2][4];
    #pragma unroll
    for (int h = 0; h < 2; ++h){
        bf16x8 xa[2];
        #pragma unroll
        for (int ks = 0; ks < 2; ++ks){
            int row = w * 16 + lr;
            int ch  = (h * 8 + ks * 4 + lk) ^ (row & 15);
            xa[ks] = *(const bf16x8*)&xs[row * 128 + ch * 8];
        }
        f32x4 Ca[2], Cg[2];
        #pragma unroll
        for (int nt = 0; nt < 2; ++nt){ Ca[nt] = (f32x4)0.f; Cg[nt] = (f32x4)0.f; }
        #pragma unroll
        for (int nt = 0; nt < 2; ++nt)
            #pragma unroll
            for (int ks = 0; ks < 2; ++ks){
                bf16x8 wfa = *(const bf16x8*)(Wab + ((size_t)(h*4 + nt*2 + ks) << 9) + lane * 8);
                bf16x8 wfb = *(const bf16x8*)(Wab + ((size_t)(8 + h*4 + nt*2 + ks) << 9) + lane * 8);
                Ca[nt] = __builtin_amdgcn_mfma_f32_16x16x32_bf16(xa[ks], wfa, Ca[nt], 0, 0, 0);
                Cg[nt] = __builtin_amdgcn_mfma_f32_16x16x32_bf16(xa[ks], wfb, Cg[nt], 0, 0, 0);
            }
        float pj[4];
        #pragma unroll
        for (int j = 0; j < 4; ++j){
            float s = 0.f;
            #pragma unroll
            for (int nt = 0; nt < 2; ++nt){
                int d = h * 32 + nt * 16 + lr;
                float av = tanhf(Ca[nt][j] + ba[d]);
                float gv = 1.f / (1.f + expf(-(Cg[nt][j] + bb[d])));
                s += av * gv * Wc[d];
            }
            pj[j] = s;
        }
        #pragma unroll
        for (int m = 1; m <= 8; m <<= 1)
            #pragma unroll
            for (int j = 0; j < 4; ++j)
                pj[j] += __shfl_xor(pj[j], m, 64);
        #pragma unroll
        for (int j = 0; j < 4; ++j){
            long row = rowBase + w * 16 + lk * 4 + j;
            // |A| <= sum|Wc|+|bc| (~7): exp safe in f32 without max-subtract
            eh[h][j] = (row < (long)N) ? expf(pj[j] + bc[h]) : 0.f;
        }
    }

    // ---- pooling: p[col] = sum over wave's 16 rows of e*x (f32 acc) ----
    float p[8];
    #pragma unroll
    for (int nt = 0; nt < 8; ++nt){
        const int h = nt >> 2;
        float s = 0.f;
        #pragma unroll
        for (int j = 0; j < 4; ++j) s += eh[h][j] * acc[nt][j];
        p[nt] = s;
    }
    #pragma unroll
    for (int m = 16; m <= 32; m <<= 1)
        #pragma unroll
        for (int nt = 0; nt < 8; ++nt)
            p[nt] += __shfl_xor(p[nt], m, 64);
    float es0 = eh[0][0] + eh[0][1] + eh[0][2] + eh[0][3];
    float es1 = eh[1][0] + eh[1][1] + eh[1][2] + eh[1][3];
    es0 += __shfl_xor(es0, 16, 64); es0 += __shfl_xor(es0, 32, 64);
    es1 += __shfl_xor(es1, 16, 64); es1 += __shfl_xor(es1, 32, 64);

    if (lk == 0){
        #pragma unroll
        for (int nt = 0; nt < 8; ++nt)
            pbuf[w * 132 + nt * 16 + lr] = p[nt];
    }
    if (lane == 0){
        pbuf[w * 132 + 128] = es0;
        pbuf[w * 132 + 129] = es1;
    }
    __syncthreads();
    if (t < 130){
        float s = pbuf[t] + pbuf[132 + t] + pbuf[264 + t] + pbuf[396 + t];
        partials[(size_t)gb * 132 + t] = s;
    }
}

// ---------------------------------------------------------------------------
// K2: first-stage reduction over blocks. 128 blocks; 2 independent accums.
// ---------------------------------------------------------------------------
__global__ __launch_bounds__(256)
void reduce1(const float* __restrict__ partials, float* __restrict__ red, int nb){
    const int b = blockIdx.x, t = threadIdx.x;
    if (t >= 130) return;
    float a0 = 0.f, a1 = 0.f;
    for (int r = b; r < nb; r += 256){
        a0 += partials[(size_t)r * 132 + t];
        if (r + 128 < nb) a1 += partials[(size_t)(r + 128) * 132 + t];
    }
    red[b * 132 + t] = a0 + a1;
}

// ---------------------------------------------------------------------------
// K3: combine 128 reduced rows (f64), M, logits, sigmoid, Y_hat. One block,
// parallel column sums + 64-lane shfl butterfly dot (fixed order).
// ---------------------------------------------------------------------------
__global__ __launch_bounds__(256)
void finalize2(const float* __restrict__ red, const float* __restrict__ Wcls,
               const float* __restrict__ bcls, float* __restrict__ out){
    __shared__ double colD[2][130];
    __shared__ float  M_s[128];
    const int t = threadIdx.x;
    const int c = t & 127, rh = t >> 7;
    {
        double s = 0.0;
        for (int r = rh * 64; r < rh * 64 + 64; r += 4){
            s += (double)red[(r + 0) * 132 + c] + (double)red[(r + 1) * 132 + c]
               + (double)red[(r + 2) * 132 + c] + (double)red[(r + 3) * 132 + c];
        }
        colD[rh][c] = s;
    }
    if (t < 4){
        int cc = 128 + (t & 1), hh = t >> 1;
        double s = 0.0;
        for (int r = hh * 64; r < hh * 64 + 64; r += 4){
            s += (double)red[(r + 0) * 132 + cc] + (double)red[(r + 1) * 132 + cc]
               + (double)red[(r + 2) * 132 + cc] + (double)red[(r + 3) * 132 + cc];
        }
        colD[hh][cc] = s;
    }
    __syncthreads();
    if (t < 128)
        M_s[t] = (float)((colD[0][t] + colD[1][t]) /
                         (colD[0][128 + (t >> 6)] + colD[1][128 + (t >> 6)]));
    __syncthreads();
    if (t < 64){
        double d = (double)M_s[t] * (double)Wcls[t]
                 + (double)M_s[t + 64] * (double)Wcls[t + 64];
        #pragma unroll
        for (int m = 1; m < 64; m <<= 1) d += __shfl_xor(d, m, 64);
        if (t == 0){
            double lg = d + (double)bcls[0];
            out[0] = (float)(1.0 / (1.0 + exp(-lg)));
            out[1] = (lg >= 0.0) ? 1.f : 0.f;
        }
    }
}

// ---------------------------------------------------------------------------
extern "C" void kernel_launch(void* const* d_in, const int* in_sizes, int n_in,
                              void* d_out, int out_size, void* d_ws, size_t ws_size,
                              hipStream_t stream){
    const float* hG   = (const float*)d_in[0];
    const float* W0   = (const float*)d_in[1];
    const float* b0   = (const float*)d_in[2];
    const float* Wa   = (const float*)d_in[3];
    const float* ba   = (const float*)d_in[4];
    const float* Wb   = (const float*)d_in[5];
    const float* bb   = (const float*)d_in[6];
    const float* Wc   = (const float*)d_in[7];
    const float* bc   = (const float*)d_in[8];
    const float* Wcls = (const float*)d_in[9];
    const float* bcls = (const float*)d_in[10];

    const int N    = in_sizes[0] / L_IN;
    const int nb64 = (N + 63) / 64;      // 64-row fused tiles

    char* ws = (char*)d_ws;
    u16* Bimg = (u16*)ws;                                  // 26*4096 u16 = 212992 B
    u16* Wab  = (u16*)(ws + 262144);                       // 16384 B
    size_t poff = 262144 + 16384;                          // 278528
    float* partials = (float*)(ws + poff);                 // nb64*132 f32
    size_t roff = poff + (((size_t)nb64 * 132 * 4 + 4095) & ~(size_t)4095);
    float* red  = (float*)(ws + roff);                     // 128*132 f32

    prep_all <<<(KT32 * 32 * 128 + 16384 + 255) / 256, 256, 0, stream>>>(W0, Wa, Wb, Bimg, Wab);
    fc_fused <<<nb64, 256, 0, stream>>>(hG, Bimg, Wab, b0, ba, bb, Wc, bc,
                                        partials, N);
    reduce1  <<<128, 256, 0, stream>>>(partials, red, nb64);
    finalize2<<<1, 256, 0, stream>>>(red, Wcls, bcls, (float*)d_out);
}

// Round 17
// 100.014 us; speedup vs baseline: 1.1687x; 1.0383x over previous
//
#include <hip/hip_runtime.h>
#include <stdint.h>
#include <math.h>

typedef unsigned short u16;
typedef unsigned int   u32;
typedef __bf16 bf16x8 __attribute__((ext_vector_type(8)));
typedef float  f32x4  __attribute__((ext_vector_type(4)));

#define L_IN 784
#define KT2 25            // 25 K-tiles of 32 (800 >= 784; pad zeros in B)

__device__ __forceinline__ u32 f2bf(float f){
    u32 u = __float_as_uint(f);
    return (u + 0x7fffu + ((u >> 16) & 1u)) >> 16;   // RNE truncate to bf16
}

__device__ __forceinline__ void gload16(const void* g, void* l){
    __builtin_amdgcn_global_load_lds(
        (const __attribute__((address_space(1))) unsigned char*)g,
        (__attribute__((address_space(3))) unsigned char*)l, 16, 0, 0);
}

// ---------------------------------------------------------------------------
// K0: merged prep, coalesced reads (validated r11-r16).
// Part 1: W0 -> Bimg fragment-broadcast bf16 at BK=32:
//   Bimg[(kt*8 + nt)*512 + lane*8 + j] = W0[k][col],
//   col = nt*16 + (lane&15), k = kt*32 + (lane>>4)*8 + j. Zero for k>=784.
// Part 2: Wa/Wb -> Wab fragment image (validated r7-r16).
// ---------------------------------------------------------------------------
__global__ void prep_all(const float* __restrict__ W0, const float* __restrict__ Wa,
                         const float* __restrict__ Wb, u16* __restrict__ Bimg,
                         u16* __restrict__ Wab){
    int idx = blockIdx.x * 256 + threadIdx.x;
    if (idx < KT2 * 32 * 128){
        int col = idx & 127, k = idx >> 7;
        float v = (k < L_IN) ? W0[idx] : 0.f;        // coalesced: idx = k*128+col
        int kt = k >> 5, lk = (k >> 3) & 3, j = k & 7;
        Bimg[((kt * 8 + (col >> 4)) << 9) + (lk * 16 + (col & 15)) * 8 + j]
            = (u16)f2bf(v);
    } else if (idx < KT2 * 32 * 128 + 16384){
        int i2 = idx - KT2 * 32 * 128;
        int jj = i2 & 7, l = (i2 >> 3) & 63, ks = (i2 >> 9) & 1;
        int nt = (i2 >> 10) & 1, h = (i2 >> 11) & 1, mat = (i2 >> 12) & 1;
        int s = ks * 32 + (l >> 4) * 8 + jj, d = nt * 16 + (l & 15);
        const float* W = mat ? Wb : Wa;
        Wab[i2] = (u16)f2bf(W[h * 2048 + s * 32 + d]);
    }
}

// ---------------------------------------------------------------------------
// K1: FUSED relu(h@W0+b0) -> gated attention -> exp -> pooling partials.
// Best-measured variant (r13, 100.4us): BK=32, both A and B DMA-staged into
// LDS; A 3 x 8KB (2-deep HBM pipeline), B 2 x 8KB (1-deep, L2-hot); 40KB
// -> 4 blocks/CU. K-loop has NO register VMEM loads: the ONLY vmcnt wait is
// the explicit end-of-tile s_waitcnt vmcnt(2), which (in-order FIFO) retires
// exactly {A(kt+1), B(kt+1)} while A(kt+2), issued at the top of tile kt,
// stays in flight ~2 tile periods. Raw s_barrier between tiles (no drain).
// ---------------------------------------------------------------------------
__global__ __launch_bounds__(256, 4)
void fc_fused(const float* __restrict__ hG, const u16* __restrict__ Bimg,
              const u16* __restrict__ Wab, const float* __restrict__ b0,
              const float* __restrict__ ba, const float* __restrict__ bb,
              const float* __restrict__ Wc, const float* __restrict__ bc,
              float* __restrict__ partials, int N){
    __shared__ __align__(16) char Asm[5 * 8192];     // A: 3 x 8KB, B: 2 x 8KB

    const int t    = threadIdx.x;
    const int lane = t & 63;
    const int w    = t >> 6;
    const int lr   = lane & 15;          // A-row / B-col within 16
    const int lk   = lane >> 4;          // k-slot 0..3 (8 k each)
    const int gb   = blockIdx.x;
    const long rowBase = (long)gb * 64;

    // ---- A staging geometry (validated r12): instr j (0,1): granule
    // g = j*256+t; row = j*32+(t>>3); slot c = t&7; src granule cs = c^(row&7)
    // -> per-thread constant. 8 fully-used 128B lines per wave-instr.
    const int cs = (t & 7) ^ ((t >> 3) & 7);
    const float* srcp[2];
    #pragma unroll
    for (int j = 0; j < 2; ++j){
        long grow = rowBase + j * 32 + (t >> 3);
        if (grow >= N) grow = N - 1;                 // clamp; e=0 masks later
        srcp[j] = hG + grow * L_IN + cs * 4;
    }
    const char* BimgB = (const char*)Bimg;

    f32x4 acc[8];
    #pragma unroll
    for (int nt = 0; nt < 8; ++nt) acc[nt] = (f32x4)0.f;

    auto stageA = [&](int kt, char* buf){
        // pad: kt==24, cs>=4 -> k>=784 invalid; read k=cs*4 (B zero-pads).
        const int off = (kt == KT2 - 1 && cs >= 4) ? 0 : kt * 32;
        #pragma unroll
        for (int j = 0; j < 2; ++j)
            gload16(srcp[j] + off, buf + (j * 256 + t) * 16);
    };
    auto stageB = [&](int kt, char* buf){
        #pragma unroll
        for (int i = 0; i < 2; ++i)
            gload16(BimgB + (size_t)kt * 8192 + i * 4096 + t * 16,
                    buf + i * 4096 + t * 16);
    };

    char* pa0 = &Asm[0];     char* pa1 = &Asm[8192];  char* pa2 = &Asm[16384];
    char* pbR = &Asm[24576]; char* pbW = &Asm[32768];

    stageA(0, pa0);
    stageA(1, pa1);
    stageB(0, pbR);
    __syncthreads();                                 // one-time full drain

    const int rA = w * 16 + lr;

    #pragma unroll 1
    for (int kt = 0; kt < KT2; ++kt){
        // ---- stage B(kt+1) then A(kt+2) at the TOP (B older than A) ----
        __builtin_amdgcn_sched_barrier(0);
        if (kt + 1 < KT2) stageB(kt + 1, pbW);
        if (kt + 2 < KT2) stageA(kt + 2, pa2);
        __builtin_amdgcn_sched_barrier(0);

        // ---- A fragment from LDS (swizzled) + cvt ----
        const char* base = pa0 + rA * 128;
        f32x4 lo = *(const f32x4*)(base + (((lk * 2)    ) ^ (rA & 7)) * 16);
        f32x4 hi = *(const f32x4*)(base + (((lk * 2) + 1) ^ (rA & 7)) * 16);
        bf16x8 af;
        #pragma unroll
        for (int j = 0; j < 4; ++j){
            af[j]     = (__bf16)lo[j];
            af[4 + j] = (__bf16)hi[j];
        }
        // ---- B fragments from LDS image (lane-linear, conflict-free) ----
        bf16x8 bfr[8];
        #pragma unroll
        for (int nt = 0; nt < 8; ++nt)
            bfr[nt] = *(const bf16x8*)(pbR + nt * 1024 + lane * 16);
        // ---- MFMA ----
        #pragma unroll
        for (int nt = 0; nt < 8; ++nt)
            acc[nt] = __builtin_amdgcn_mfma_f32_16x16x32_bf16(af, bfr[nt], acc[nt], 0, 0, 0);

        // ---- end-of-tile: retire {A(kt+1), B(kt+1)}, keep A(kt+2) flying ----
        if (kt + 1 < KT2){
            if (kt + 2 < KT2) asm volatile("s_waitcnt vmcnt(2)" ::: "memory");
            else              asm volatile("s_waitcnt vmcnt(0)" ::: "memory");
            __builtin_amdgcn_sched_barrier(0);
            __builtin_amdgcn_s_barrier();
            __builtin_amdgcn_sched_barrier(0);
        }
        // rotate: A 3-cycle, B 2-cycle
        char* ta = pa0; pa0 = pa1; pa1 = pa2; pa2 = ta;
        char* tb = pbR; pbR = pbW; pbW = tb;
    }

    __syncthreads();   // all DMAs retired; LDS reusable

    // ---- bias + relu; x-tile bf16 into Asm[0..16K) (swizzled) ----
    u16*   xs   = (u16*)&Asm[0];          // 64 x 128 bf16 = 16 KB
    float* pbuf = (float*)&Asm[24576];    // 4 x 132 f32 cross-wave buffer
    #pragma unroll
    for (int nt = 0; nt < 8; ++nt){
        float bias = b0[nt * 16 + lr];
        #pragma unroll
        for (int j = 0; j < 4; ++j){
            float v = acc[nt][j] + bias;
            v = v > 0.f ? v : 0.f;
            acc[nt][j] = v;
            int row = w * 16 + lk * 4 + j;
            int col = nt * 16 + lr;
            xs[row * 128 + ((((col >> 3) ^ (row & 15))) << 3) + (col & 7)] = (u16)f2bf(v);
        }
    }
    __syncthreads();

    // ---- per-head projections via MFMA + logits + exp (validated r7) ----
    float eh[2][4];
    #pragma unroll
    for (int h = 0; h < 2; ++h){
        bf16x8 xa[2];
        #pragma unroll
        for (int ks = 0; ks < 2; ++ks){
            int row = w * 16 + lr;
            int ch  = (h * 8 + ks * 4 + lk) ^ (row & 15);
            xa[ks] = *(const bf16x8*)&xs[row * 128 + ch * 8];
        }
        f32x4 Ca[2], Cg[2];
        #pragma unroll
        for (int nt = 0; nt < 2; ++nt){ Ca[nt] = (f32x4)0.f; Cg[nt] = (f32x4)0.f; }
        #pragma unroll
        for (int nt = 0; nt < 2; ++nt)
            #pragma unroll
            for (int ks = 0; ks < 2; ++ks){
                bf16x8 wfa = *(const bf16x8*)(Wab + ((size_t)(h*4 + nt*2 + ks) << 9) + lane * 8);
                bf16x8 wfb = *(const bf16x8*)(Wab + ((size_t)(8 + h*4 + nt*2 + ks) << 9) + lane * 8);
                Ca[nt] = __builtin_amdgcn_mfma_f32_16x16x32_bf16(xa[ks], wfa, Ca[nt], 0, 0, 0);
                Cg[nt] = __builtin_amdgcn_mfma_f32_16x16x32_bf16(xa[ks], wfb, Cg[nt], 0, 0, 0);
            }
        float pj[4];
        #pragma unroll
        for (int j = 0; j < 4; ++j){
            float s = 0.f;
            #pragma unroll
            for (int nt = 0; nt < 2; ++nt){
                int d = h * 32 + nt * 16 + lr;
                float av = tanhf(Ca[nt][j] + ba[d]);
                float gv = 1.f / (1.f + expf(-(Cg[nt][j] + bb[d])));
                s += av * gv * Wc[d];
            }
            pj[j] = s;
        }
        #pragma unroll
        for (int m = 1; m <= 8; m <<= 1)
            #pragma unroll
            for (int j = 0; j < 4; ++j)
                pj[j] += __shfl_xor(pj[j], m, 64);
        #pragma unroll
        for (int j = 0; j < 4; ++j){
            long row = rowBase + w * 16 + lk * 4 + j;
            // |A| <= sum|Wc|+|bc| (~7): exp safe in f32 without max-subtract
            eh[h][j] = (row < (long)N) ? expf(pj[j] + bc[h]) : 0.f;
        }
    }

    // ---- pooling: p[col] = sum over wave's 16 rows of e*x (f32 acc) ----
    float p[8];
    #pragma unroll
    for (int nt = 0; nt < 8; ++nt){
        const int h = nt >> 2;
        float s = 0.f;
        #pragma unroll
        for (int j = 0; j < 4; ++j) s += eh[h][j] * acc[nt][j];
        p[nt] = s;
    }
    #pragma unroll
    for (int m = 16; m <= 32; m <<= 1)
        #pragma unroll
        for (int nt = 0; nt < 8; ++nt)
            p[nt] += __shfl_xor(p[nt], m, 64);
    float es0 = eh[0][0] + eh[0][1] + eh[0][2] + eh[0][3];
    float es1 = eh[1][0] + eh[1][1] + eh[1][2] + eh[1][3];
    es0 += __shfl_xor(es0, 16, 64); es0 += __shfl_xor(es0, 32, 64);
    es1 += __shfl_xor(es1, 16, 64); es1 += __shfl_xor(es1, 32, 64);

    if (lk == 0){
        #pragma unroll
        for (int nt = 0; nt < 8; ++nt)
            pbuf[w * 132 + nt * 16 + lr] = p[nt];
    }
    if (lane == 0){
        pbuf[w * 132 + 128] = es0;
        pbuf[w * 132 + 129] = es1;
    }
    __syncthreads();
    if (t < 130){
        float s = pbuf[t] + pbuf[132 + t] + pbuf[264 + t] + pbuf[396 + t];
        partials[(size_t)gb * 132 + t] = s;
    }
}

// ---------------------------------------------------------------------------
// K2: first-stage reduction over blocks. 128 blocks; 2 independent accums.
// ---------------------------------------------------------------------------
__global__ __launch_bounds__(256)
void reduce1(const float* __restrict__ partials, float* __restrict__ red, int nb){
    const int b = blockIdx.x, t = threadIdx.x;
    if (t >= 130) return;
    float a0 = 0.f, a1 = 0.f;
    for (int r = b; r < nb; r += 256){
        a0 += partials[(size_t)r * 132 + t];
        if (r + 128 < nb) a1 += partials[(size_t)(r + 128) * 132 + t];
    }
    red[b * 132 + t] = a0 + a1;
}

// ---------------------------------------------------------------------------
// K3: combine 128 reduced rows (f64), M, logits, sigmoid, Y_hat. One block,
// parallel column sums + 64-lane shfl butterfly dot (fixed order).
// ---------------------------------------------------------------------------
__global__ __launch_bounds__(256)
void finalize2(const float* __restrict__ red, const float* __restrict__ Wcls,
               const float* __restrict__ bcls, float* __restrict__ out){
    __shared__ double colD[2][130];
    __shared__ float  M_s[128];
    const int t = threadIdx.x;
    const int c = t & 127, rh = t >> 7;
    {
        double s = 0.0;
        for (int r = rh * 64; r < rh * 64 + 64; r += 4){
            s += (double)red[(r + 0) * 132 + c] + (double)red[(r + 1) * 132 + c]
               + (double)red[(r + 2) * 132 + c] + (double)red[(r + 3) * 132 + c];
        }
        colD[rh][c] = s;
    }
    if (t < 4){
        int cc = 128 + (t & 1), hh = t >> 1;
        double s = 0.0;
        for (int r = hh * 64; r < hh * 64 + 64; r += 4){
            s += (double)red[(r + 0) * 132 + cc] + (double)red[(r + 1) * 132 + cc]
               + (double)red[(r + 2) * 132 + cc] + (double)red[(r + 3) * 132 + cc];
        }
        colD[hh][cc] = s;
    }
    __syncthreads();
    if (t < 128)
        M_s[t] = (float)((colD[0][t] + colD[1][t]) /
                         (colD[0][128 + (t >> 6)] + colD[1][128 + (t >> 6)]));
    __syncthreads();
    if (t < 64){
        double d = (double)M_s[t] * (double)Wcls[t]
                 + (double)M_s[t + 64] * (double)Wcls[t + 64];
        #pragma unroll
        for (int m = 1; m < 64; m <<= 1) d += __shfl_xor(d, m, 64);
        if (t == 0){
            double lg = d + (double)bcls[0];
            out[0] = (float)(1.0 / (1.0 + exp(-lg)));
            out[1] = (lg >= 0.0) ? 1.f : 0.f;
        }
    }
}

// ---------------------------------------------------------------------------
extern "C" void kernel_launch(void* const* d_in, const int* in_sizes, int n_in,
                              void* d_out, int out_size, void* d_ws, size_t ws_size,
                              hipStream_t stream){
    const float* hG   = (const float*)d_in[0];
    const float* W0   = (const float*)d_in[1];
    const float* b0   = (const float*)d_in[2];
    const float* Wa   = (const float*)d_in[3];
    const float* ba   = (const float*)d_in[4];
    const float* Wb   = (const float*)d_in[5];
    const float* bb   = (const float*)d_in[6];
    const float* Wc   = (const float*)d_in[7];
    const float* bc   = (const float*)d_in[8];
    const float* Wcls = (const float*)d_in[9];
    const float* bcls = (const float*)d_in[10];

    const int N    = in_sizes[0] / L_IN;
    const int nb64 = (N + 63) / 64;      // 64-row fused tiles

    char* ws = (char*)d_ws;
    u16* Bimg = (u16*)ws;                                  // 25*4096 u16 = 204800 B
    u16* Wab  = (u16*)(ws + 262144);                       // 16384 B
    size_t poff = 262144 + 16384;                          // 278528
    float* partials = (float*)(ws + poff);                 // nb64*132 f32
    size_t roff = poff + (((size_t)nb64 * 132 * 4 + 4095) & ~(size_t)4095);
    float* red  = (float*)(ws + roff);                     // 128*132 f32

    prep_all <<<(KT2 * 32 * 128 + 16384 + 255) / 256, 256, 0, stream>>>(W0, Wa, Wb, Bimg, Wab);
    fc_fused <<<nb64, 256, 0, stream>>>(hG, Bimg, Wab, b0, ba, bb, Wc, bc,
                                        partials, N);
    reduce1  <<<128, 256, 0, stream>>>(partials, red, nb64);
    finalize2<<<1, 256, 0, stream>>>(red, Wcls, bcls, (float*)d_out);
}